// Round 2
// baseline (134.073 us; speedup 1.0000x reference)
//
#include <hip/hip_runtime.h>
#include <math.h>

#define KS   65536
#define TS   96
#define TPB  256
#define NBLK (KS / TPB)   /* 256 */

#define MSR 0.196f            /* 9.8 * 0.02, f64->f32 */
#define WSM 17.0f
#define DTF 0.02f

static __device__ __forceinline__ float clampf(float v, float lo, float hi) {
  return fminf(fmaxf(v, lo), hi);
}

/* ws layout (floats):
   [0, KS*4)            per-k {cost_total, noise[k,0,0], noise[k,0,1], pad}
   [KS*4, KS*4+NBLK)    per-block cost min
   [KS*4+NBLK, +3)      accumulators {sum_w, sum_w*n0, sum_w*n1}            */

__global__ __launch_bounds__(TPB) void mppi_rollout(
    const float* __restrict__ state, const float* __restrict__ U,
    const float* __restrict__ noise, const float* __restrict__ nsi,
    const float* __restrict__ bev,   const float* __restrict__ goal,
    float* __restrict__ ws)
{
  /* MAX_CURV_RATE exactly as the reference computes it: f64 all the way,
     rounded to f32 at jnp op time. Constant-folded by the compiler. */
  const float MCR = (float)(tan(30.0 / 57.3) / (0.24 + 0.24) * 20.0 * 0.02);

  __shared__ float s_bev[2500];
  __shared__ float s_u0[TS], s_u1[TS], s_g0[TS], s_g1[TS];

  const int tid = threadIdx.x;
  if (tid < TS) {
    float u0 = 0.f, u1 = 0.f;
    if (tid < TS - 1) { u0 = U[(tid + 1) * 2 + 0]; u1 = U[(tid + 1) * 2 + 1]; }
    s_u0[tid] = u0; s_u1[tid] = u1;
    /* g[t][v] = sum_v U_rolled[t][v] * nsi[u][v]  (action-cost contraction) */
    s_g0[tid] = u0 * nsi[0] + u1 * nsi[1];
    s_g1[tid] = u0 * nsi[2] + u1 * nsi[3];
  }
  for (int i = tid; i < 2500; i += TPB) s_bev[i] = bev[i];
  if (blockIdx.x == 0 && tid < 3) ws[(size_t)KS * 4 + NBLK + tid] = 0.f;
  __syncthreads();

  const int k = blockIdx.x * TPB + tid;
  const float4* __restrict__ nrow = (const float4*)(noise + (size_t)k * (TS * 2));

  const float gx = goal[0], gy = goal[1];
  float x = state[0], y = state[1], yaw = state[5];

  float4 v = nrow[0];
  const float n00 = v.x, n01 = v.y;

  float c_acc = 0.f, s_acc = 0.f;
  float craw = (s_u0[0] + v.x) * MCR;
  float sraw = (s_u1[0] + v.y) * WSM;
  float cost = 0.f, acost = 0.f, dist = 0.f;

#define STEP(CU, SU) do {                                   \
    yaw += (SU) * (CU) * DTF;                               \
    float sn_, cs_; sincosf(yaw, &sn_, &cs_);               \
    x += (SU) * cs_ * DTF;                                  \
    y += (SU) * sn_ * DTF;                                  \
    float dx_ = x - gx, dy_ = y - gy;                       \
    dist = sqrtf(dx_ * dx_ + dy_ * dy_);                    \
    int ix_ = (int)(x / 0.4f + 25.0f);                      \
    int iy_ = (int)(y / 0.4f + 25.0f);                      \
    ix_ = min(max(ix_, 0), 49); iy_ = min(max(iy_, 0), 49); \
    cost += s_bev[iy_ * 50 + ix_] + 0.1f * dist;            \
  } while (0)

  for (int i = 0; i < 47; ++i) {
    const float4 vn = nrow[i + 1];
    const int t = 2 * i;
    { /* t even: raw at t+1 comes from v.z/v.w */
      float crn = (s_u0[t + 1] + v.z) * MCR;
      float srn = (s_u1[t + 1] + v.w) * WSM;
      c_acc += clampf(crn - craw, -MCR, MCR);
      s_acc += clampf(srn - sraw, -MSR, MSR);
      craw = crn; sraw = srn;
      acost += v.x * s_g0[t] + v.y * s_g1[t];
      STEP(c_acc, s_acc);
    }
    { /* t odd: raw at t+2 comes from vn.x/vn.y */
      float crn = (s_u0[t + 2] + vn.x) * MCR;
      float srn = (s_u1[t + 2] + vn.y) * WSM;
      c_acc += clampf(crn - craw, -MCR, MCR);
      s_acc += clampf(srn - sraw, -MSR, MSR);
      craw = crn; sraw = srn;
      acost += v.z * s_g0[t + 1] + v.w * s_g1[t + 1];
      STEP(c_acc, s_acc);
    }
    v = vn;
  }
  { /* epilogue: t=94 (needs raw[95] = v.z/v.w), then t=95 (uses last raw) */
    float crn = (s_u0[95] + v.z) * MCR;
    float srn = (s_u1[95] + v.w) * WSM;
    c_acc += clampf(crn - craw, -MCR, MCR);
    s_acc += clampf(srn - sraw, -MSR, MSR);
    craw = crn; sraw = srn;
    acost += v.x * s_g0[94] + v.y * s_g1[94];
    STEP(c_acc, s_acc);
    acost += v.z * s_g0[95] + v.w * s_g1[95];
    STEP(craw, sraw);   /* c[:, :, -1:] = last raw value */
  }
#undef STEP

  const float cost_total = cost + dist + acost;  /* dist holds t=95 -> terminal */
  float4 o; o.x = cost_total; o.y = n00; o.z = n01; o.w = 0.f;
  ((float4*)ws)[k] = o;

  /* block-level min */
  float m = cost_total;
  #pragma unroll
  for (int off = 32; off >= 1; off >>= 1) m = fminf(m, __shfl_xor(m, off));
  __shared__ float s_m[TPB / 64];
  if ((tid & 63) == 0) s_m[tid >> 6] = m;
  __syncthreads();
  if (tid == 0) {
    float bm = s_m[0];
    for (int w = 1; w < TPB / 64; ++w) bm = fminf(bm, s_m[w]);
    ws[(size_t)KS * 4 + blockIdx.x] = bm;
  }
}

__global__ __launch_bounds__(TPB) void mppi_weight(
    const float* __restrict__ ws, float* __restrict__ acc)
{
  const int tid = threadIdx.x;
  /* beta: every block redundantly reduces the 256 block mins (L2-hot) */
  const float* mins = ws + (size_t)KS * 4;
  float m = mins[tid];
  #pragma unroll
  for (int off = 32; off >= 1; off >>= 1) m = fminf(m, __shfl_xor(m, off));
  __shared__ float s_m[TPB / 64];
  if ((tid & 63) == 0) s_m[tid >> 6] = m;
  __syncthreads();
  const float beta = fminf(fminf(s_m[0], s_m[1]), fminf(s_m[2], s_m[3]));

  const int k = blockIdx.x * TPB + tid;
  const float4 v = ((const float4*)ws)[k];
  const float w = expf(beta - v.x);     /* = exp(-(cost-beta)/LAMBDA), LAMBDA=1 */
  float s0 = w, s1 = w * v.y, s2 = w * v.z;
  #pragma unroll
  for (int off = 32; off >= 1; off >>= 1) {
    s0 += __shfl_xor(s0, off);
    s1 += __shfl_xor(s1, off);
    s2 += __shfl_xor(s2, off);
  }
  __shared__ float s_p[TPB / 64][3];
  if ((tid & 63) == 0) { s_p[tid >> 6][0] = s0; s_p[tid >> 6][1] = s1; s_p[tid >> 6][2] = s2; }
  __syncthreads();
  if (tid == 0) {
    float a0 = 0.f, a1 = 0.f, a2 = 0.f;
    for (int w2 = 0; w2 < TPB / 64; ++w2) { a0 += s_p[w2][0]; a1 += s_p[w2][1]; a2 += s_p[w2][2]; }
    atomicAdd(&acc[0], a0); atomicAdd(&acc[1], a1); atomicAdd(&acc[2], a2);
  }
}

__global__ void mppi_final(const float* __restrict__ U,
                           const float* __restrict__ acc,
                           float* __restrict__ out)
{
  if (threadIdx.x == 0) {
    const float inv = 1.0f / acc[0];
    out[0] = U[2] + acc[1] * inv;   /* U_rolled[0] = U_orig[1] */
    out[1] = U[3] + acc[2] * inv;
  }
}

extern "C" void kernel_launch(void* const* d_in, const int* in_sizes, int n_in,
                              void* d_out, int out_size, void* d_ws, size_t ws_size,
                              hipStream_t stream)
{
  const float* state = (const float*)d_in[0];
  const float* U     = (const float*)d_in[1];
  const float* noise = (const float*)d_in[2];
  const float* nsi   = (const float*)d_in[3];
  const float* bev   = (const float*)d_in[4];
  const float* goal  = (const float*)d_in[5];
  /* d_in[6] (last_action) only writes state[15:17], which never affects x/y/yaw */

  float* ws  = (float*)d_ws;
  float* out = (float*)d_out;
  float* acc = ws + (size_t)KS * 4 + NBLK;

  mppi_rollout<<<NBLK, TPB, 0, stream>>>(state, U, noise, nsi, bev, goal, ws);
  mppi_weight<<<NBLK, TPB, 0, stream>>>(ws, acc);
  mppi_final<<<1, 64, 0, stream>>>(U, acc, out);
}